// Round 6
// baseline (196.041 us; speedup 1.0000x reference)
//
#include <hip/hip_runtime.h>

typedef _Float16 half2v __attribute__((ext_vector_type(2)));
typedef _Float16 half8  __attribute__((ext_vector_type(8)));
typedef float    floatx4 __attribute__((ext_vector_type(4)));

// ---------------- ws layout (fast path) ----------------
// [0, 25600000)            tab:  normalized fp16 table, 100000 x 128 (slice s = rows [s*12500,(s+1)*12500))
// [25600000, 26124288)     qtab: normalized fp16 query rows, 128 x 16 x 128
// [26124288, 26214400)     pooled: [128][176] fp32
#define TAB_OFF   0
#define QTAB_OFF  25600000
#define POOL_OFF  26124288
#define WS_NEEDED 26214400

// ---- prep: XCD-sliced normalize (block g -> slice g&7 stays L2-local); qtab; zero pooled ----
__global__ __launch_bounds__(256) void knrm_prep(
    const float* __restrict__ emb,       // 100000 x 128
    const int*   __restrict__ queries,   // 128 x 16
    _Float16*    __restrict__ tab,
    _Float16*    __restrict__ qtab,
    float*       __restrict__ pooled)    // 22528 floats
{
    const int g = blockIdx.x, tid = threadIdx.x;
    if (g < 88) pooled[g * 256 + tid] = 0.0f;

    const int lane = tid & 63;
    const int wave = tid >> 6;

    if (g < 2048) {
        const int s   = g & 7;                      // slice == XCD under round-robin
        const int wid = (g >> 3) * 4 + wave;        // 0..1023 within slice
        for (int i = wid; i < 12500; i += 1024) {
            const int row = s * 12500 + i;
            const float x = __builtin_nontemporal_load(emb + (size_t)row * 128 + lane * 2);
            const float y = __builtin_nontemporal_load(emb + (size_t)row * 128 + lane * 2 + 1);
            float ns = x * x + y * y;
            ns += __shfl_xor(ns, 1);  ns += __shfl_xor(ns, 2);
            ns += __shfl_xor(ns, 4);  ns += __shfl_xor(ns, 8);
            ns += __shfl_xor(ns, 16); ns += __shfl_xor(ns, 32);
            const float sc = (ns > 0.0f) ? __frsqrt_rn(ns) : 0.0f;
            half2v h; h[0] = (_Float16)(x * sc); h[1] = (_Float16)(y * sc);
            *((half2v*)(tab + (size_t)row * 128) + lane) = h;   // cached write -> local L2
        }
    } else {                                        // blocks 2048..2175: qtab for batch b
        const int b = g - 2048;
        for (int q = wave; q < 16; q += 4) {
            const int row = queries[b * 16 + q];
            const float x = __builtin_nontemporal_load(emb + (size_t)row * 128 + lane * 2);
            const float y = __builtin_nontemporal_load(emb + (size_t)row * 128 + lane * 2 + 1);
            float ns = x * x + y * y;
            ns += __shfl_xor(ns, 1);  ns += __shfl_xor(ns, 2);
            ns += __shfl_xor(ns, 4);  ns += __shfl_xor(ns, 8);
            ns += __shfl_xor(ns, 16); ns += __shfl_xor(ns, 32);
            const float sc = (ns > 0.0f) ? __frsqrt_rn(ns) : 0.0f;
            half2v h; h[0] = (_Float16)(x * sc); h[1] = (_Float16)(y * sc);
            *((half2v*)(qtab + ((size_t)b * 16 + q) * 128) + lane) = h;
        }
    }
}

// ---- main: block = (batch, slice). Compact in-slice tokens, gather from XCD-local L2 ----
__global__ __launch_bounds__(256) void knrm_main(
    const int*      __restrict__ documents,  // 128 x 2048
    const _Float16* __restrict__ tab,        // normalized
    const _Float16* __restrict__ qtab,       // normalized
    float*          __restrict__ pooled)     // [128][176]
{
    __shared__ __align__(16) _Float16 Qs[16][136];
    __shared__ __align__(16) _Float16 Ds[4][16][136];  // wave-private staging
    __shared__ int   list_s[2048];
    __shared__ int   cnt_s;
    __shared__ float pooled_s[176];

    const int tid = threadIdx.x;
    const int s   = blockIdx.x & 7;     // slice == XCD under round-robin
    const int b   = blockIdx.x >> 3;

    if (tid == 0) cnt_s = 0;
    if (tid < 176) pooled_s[tid] = 0.0f;
    {   // stage this batch's normalized Q rows (coalesced from qtab)
        const int row = tid >> 4, chunk = tid & 15;
        *(uint4*)&Qs[row][chunk * 8] =
            *(const uint4*)(qtab + ((size_t)b * 16 + row) * 128 + chunk * 8);
    }
    __syncthreads();

    const int lane = tid & 63;
    const int wave = tid >> 6;

    // ---- ballot-compact the ~256 in-slice tokens into list_s (order irrelevant: pooled is a sum) ----
    const unsigned lo = (unsigned)(s * 12500);
    for (int r = 0; r < 8; ++r) {
        const int idx = documents[b * 2048 + r * 256 + tid];
        const bool hit = ((unsigned)idx - lo) < 12500u;
        const unsigned long long mask = __ballot(hit);
        const int prefix = __popcll(mask & ((1ull << lane) - 1ull));
        int base = 0;
        if (lane == 0 && mask) base = atomicAdd(&cnt_s, __popcll(mask));
        base = __shfl(base, 0);
        if (hit) list_s[base + prefix] = idx;
    }
    __syncthreads();
    const int cnt = cnt_s;
    const int M   = (cnt + 15) >> 4;    // 16-token chunks

    const int col  = lane & 15;   // MFMA: token
    const int quad = lane >> 4;   // MFMA: k-octet / C row group

    half8 afrag[4];
#pragma unroll
    for (int c = 0; c < 4; ++c)
        afrag[c] = *(const half8*)&Qs[col][c * 32 + quad * 8];

    float pr[4][11];
#pragma unroll
    for (int r = 0; r < 4; ++r)
#pragma unroll
        for (int k = 0; k < 11; ++k) pr[r][k] = 0.0f;

    const int rsel  = lane >> 4;   // 4 rows per gather instr
    const int chunk = lane & 15;   // 16B chunk within row

    for (int c = wave; c < M; c += 4) {
        // gather 16 rows (4 instrs x 1 KB) from the XCD-local slice
#pragma unroll
        for (int j = 0; j < 4; ++j) {
            const int p   = c * 16 + j * 4 + rsel;
            const int idx = (p < cnt) ? list_s[p] : 0;   // pad -> row 0 (masked below)
            *(uint4*)&Ds[wave][j * 4 + rsel][chunk * 8] =
                *(const uint4*)(tab + (size_t)idx * 128 + chunk * 8);
        }
        // same-wave DS ordering: fragment reads below follow writes in program order
        floatx4 acc = {0.0f, 0.0f, 0.0f, 0.0f};
#pragma unroll
        for (int cc = 0; cc < 4; ++cc) {
            half8 bf = *(const half8*)&Ds[wave][col][cc * 32 + quad * 8];
            acc = __builtin_amdgcn_mfma_f32_16x16x32_f16(afrag[cc], bf, acc, 0, 0, 0);
        }
        if (c * 16 + col < cnt) {   // mask pad slots (only last chunk diverges)
#pragma unroll
            for (int r = 0; r < 4; ++r) {
                const float sim = acc[r];
#pragma unroll
                for (int k = 0; k < 11; ++k) {
                    const float tt = sim - (-1.0f + 0.2f * (float)k);
                    pr[r][k] += __builtin_amdgcn_exp2f(tt * tt * -72.13475204444817f);
                }
            }
        }
    }

#pragma unroll
    for (int r = 0; r < 4; ++r)
#pragma unroll
        for (int k = 0; k < 11; ++k)
            atomicAdd(&pooled_s[(quad * 4 + r) * 11 + k], pr[r][k]);
    __syncthreads();
    if (tid < 176) atomicAdd(&pooled[b * 176 + tid], pooled_s[tid]);
}

// ---- final: one wave per batch; coalesced [128][176] reads ----
__global__ __launch_bounds__(256) void knrm_final(
    const float* __restrict__ pooled,   // [128][176]
    const float* __restrict__ W,
    const float* __restrict__ bias,
    float*       __restrict__ out)
{
    const int tid   = threadIdx.x;
    const int lane  = tid & 63;
    const int batch = blockIdx.x * 4 + (tid >> 6);
    const float* pb = pooled + (size_t)batch * 176;

    float acc = 0.0f;
#pragma unroll
    for (int i = 0; i < 3; ++i) {
        const int f = lane + i * 64;
        if (f < 176)
            acc += __builtin_amdgcn_logf(pb[f]) * W[f % 11];   // log2
    }
    acc += __shfl_xor(acc, 1);  acc += __shfl_xor(acc, 2);
    acc += __shfl_xor(acc, 4);  acc += __shfl_xor(acc, 8);
    acc += __shfl_xor(acc, 16); acc += __shfl_xor(acc, 32);
    if (lane == 0) {
        const float t = acc * 0.69314718055994531f + bias[0];
        out[batch] = __builtin_amdgcn_rcpf(1.0f + __builtin_amdgcn_exp2f(t * -1.4426950408889634f));
    }
}

// ---- fallback path (ws too small): fp32 direct gather with inline norms ----
__global__ __launch_bounds__(256) void knrm_zero_fb(float* __restrict__ p) {
    p[blockIdx.x * 256 + threadIdx.x] = 0.0f;
}

typedef _Float16 half4v __attribute__((ext_vector_type(4)));

__global__ __launch_bounds__(256) void knrm_main_fb(
    const int*   __restrict__ queries,
    const int*   __restrict__ documents,
    const float* __restrict__ emb,
    float*       __restrict__ pooled)    // [128][176]
{
    __shared__ __align__(16) _Float16 Qs[16][136];
    __shared__ __align__(16) _Float16 Ds[4][16][136];
    __shared__ float qn_s[16];
    __shared__ float dn_s[4][16];
    __shared__ float pooled_s[176];

    const int tid  = threadIdx.x;
    const int b    = blockIdx.x >> 3;
    const int tok0 = (blockIdx.x & 7) * 256;

    {
        const int row = tid >> 4, sub = tid & 15;
        const int qi = queries[b * 16 + row];
        const float4* src = (const float4*)(emb + (size_t)qi * 128 + sub * 8);
        float4 v0 = src[0], v1 = src[1];
        half8 h;
        h[0] = (_Float16)v0.x; h[1] = (_Float16)v0.y;
        h[2] = (_Float16)v0.z; h[3] = (_Float16)v0.w;
        h[4] = (_Float16)v1.x; h[5] = (_Float16)v1.y;
        h[6] = (_Float16)v1.z; h[7] = (_Float16)v1.w;
        *(half8*)&Qs[row][sub * 8] = h;
        float ns = v0.x*v0.x + v0.y*v0.y + v0.z*v0.z + v0.w*v0.w
                 + v1.x*v1.x + v1.y*v1.y + v1.z*v1.z + v1.w*v1.w;
        ns += __shfl_xor(ns, 1); ns += __shfl_xor(ns, 2);
        ns += __shfl_xor(ns, 4); ns += __shfl_xor(ns, 8);
        if (sub == 0) qn_s[row] = sqrtf(ns);
    }
    if (tid < 176) pooled_s[tid] = 0.0f;
    __syncthreads();

    const int lane = tid & 63;
    const int wave = tid >> 6;
    const int col  = lane & 15;
    const int quad = lane >> 4;

    half8 afrag[4];
#pragma unroll
    for (int c = 0; c < 4; ++c)
        afrag[c] = *(const half8*)&Qs[col][c * 32 + quad * 8];
    float qn[4];
#pragma unroll
    for (int r = 0; r < 4; ++r) qn[r] = qn_s[quad * 4 + r];

    float pr[4][11];
#pragma unroll
    for (int r = 0; r < 4; ++r)
#pragma unroll
        for (int k = 0; k < 11; ++k) pr[r][k] = 0.0f;

    const int my_idx = documents[b * 2048 + tok0 + wave * 64 + lane];
    const int halfw = lane >> 5;
    const int sub   = lane & 31;

    for (int t = 0; t < 4; ++t) {
        float4 v[8];
#pragma unroll
        for (int k = 0; k < 8; ++k) {
            const int ridx = __shfl(my_idx, t * 16 + 2 * k + halfw);
            v[k] = *(const float4*)(emb + (size_t)ridx * 128 + sub * 4);
        }
#pragma unroll
        for (int k = 0; k < 8; ++k) {
            const float4 a = v[k];
            half4v h;
            h[0] = (_Float16)a.x; h[1] = (_Float16)a.y;
            h[2] = (_Float16)a.z; h[3] = (_Float16)a.w;
            *(half4v*)&Ds[wave][2 * k + halfw][sub * 4] = h;
            float ns = a.x*a.x + a.y*a.y + a.z*a.z + a.w*a.w;
            ns += __shfl_xor(ns, 1);  ns += __shfl_xor(ns, 2);
            ns += __shfl_xor(ns, 4);  ns += __shfl_xor(ns, 8);
            ns += __shfl_xor(ns, 16);
            if (sub == 0) dn_s[wave][2 * k + halfw] = sqrtf(ns);
        }
        floatx4 acc = {0.0f, 0.0f, 0.0f, 0.0f};
#pragma unroll
        for (int c = 0; c < 4; ++c) {
            half8 bf = *(const half8*)&Ds[wave][col][c * 32 + quad * 8];
            acc = __builtin_amdgcn_mfma_f32_16x16x32_f16(afrag[c], bf, acc, 0, 0, 0);
        }
        const float dn = dn_s[wave][col];
#pragma unroll
        for (int r = 0; r < 4; ++r) {
            const float denom = qn[r] * dn + 1e-8f;
            const float sim = acc[r] * __builtin_amdgcn_rcpf(denom);
#pragma unroll
            for (int k = 0; k < 11; ++k) {
                const float tt = sim - (-1.0f + 0.2f * (float)k);
                pr[r][k] += __builtin_amdgcn_exp2f(tt * tt * -72.13475204444817f);
            }
        }
    }
#pragma unroll
    for (int r = 0; r < 4; ++r)
#pragma unroll
        for (int k = 0; k < 11; ++k)
            atomicAdd(&pooled_s[(quad * 4 + r) * 11 + k], pr[r][k]);
    __syncthreads();
    if (tid < 176) atomicAdd(&pooled[b * 176 + tid], pooled_s[tid]);
}

extern "C" void kernel_launch(void* const* d_in, const int* in_sizes, int n_in,
                              void* d_out, int out_size, void* d_ws, size_t ws_size,
                              hipStream_t stream) {
    const int*   queries   = (const int*)d_in[0];
    const int*   documents = (const int*)d_in[1];
    const float* emb       = (const float*)d_in[2];
    const float* W         = (const float*)d_in[3];
    const float* bias      = (const float*)d_in[4];
    float* out = (float*)d_out;
    char*  ws  = (char*)d_ws;

    if (ws_size >= (size_t)WS_NEEDED) {
        _Float16* tab    = (_Float16*)(ws + TAB_OFF);
        _Float16* qtab   = (_Float16*)(ws + QTAB_OFF);
        float*    pooled = (float*)(ws + POOL_OFF);
        knrm_prep<<<2176, 256, 0, stream>>>(emb, queries, tab, qtab, pooled);
        knrm_main<<<1024, 256, 0, stream>>>(documents, tab, qtab, pooled);
        knrm_final<<<32, 256, 0, stream>>>(pooled, W, bias, out);
    } else {
        float* pooled = (float*)ws;   // 88 KiB
        knrm_zero_fb<<<88, 256, 0, stream>>>(pooled);
        knrm_main_fb<<<1024, 256, 0, stream>>>(queries, documents, emb, pooled);
        knrm_final<<<32, 256, 0, stream>>>(pooled, W, bias, out);
    }
}